// Round 1
// baseline (119.452 us; speedup 1.0000x reference)
//
#include <hip/hip_runtime.h>
#include <math.h>

#define BB 64
#define SS 8192
#define IN_DIM 512
#define OUT_DIM 128
#define DVV 128
#define CHUNK 256
#define NCHUNK (SS / CHUNK)   // 32

// Kernel 1: qt[b] = (Wk @ (q[b] @ Wq)) / sqrt(OUT_DIM)
__global__ void qt_kernel(const float* __restrict__ q,
                          const float* __restrict__ Wq,
                          const float* __restrict__ Wk,
                          float* __restrict__ qt) {
    int b = blockIdx.x;
    int e = threadIdx.x;  // 0..127
    __shared__ float qs[OUT_DIM];
    const float* qb = q + (size_t)b * IN_DIM;
    float acc = 0.f;
    for (int i = 0; i < IN_DIM; ++i)
        acc = fmaf(qb[i], Wq[(size_t)i * OUT_DIM + e], acc);
    qs[e] = acc;
    __syncthreads();
    // qt[d] = sum_e Wk[d][e] * query[e]
    float a2 = 0.f;
    const float* wkrow = Wk + (size_t)e * OUT_DIM;
    for (int i = 0; i < OUT_DIM; ++i)
        a2 = fmaf(wkrow[i], qs[i], a2);
    qt[(size_t)b * OUT_DIM + e] = a2 * 0.08838834764831845f;  // 1/sqrt(128)
}

// Kernel 2: per (b, chunk): scores -> local softmax -> partial context
__global__ __launch_bounds__(256) void partial_kernel(
    const float* __restrict__ k, const float* __restrict__ v,
    const float* __restrict__ qt, float* __restrict__ ml,
    float* __restrict__ ctx) {
    int blk = blockIdx.x;
    int b = blk / NCHUNK;
    int c = blk % NCHUNK;
    int s0 = c * CHUNK;
    int t = threadIdx.x;
    int wave = t >> 6, lane = t & 63, half = lane >> 5, l32 = lane & 31;

    __shared__ float4 qts4[OUT_DIM / 4];
    __shared__ float sc[CHUNK];
    __shared__ float4 red[256];
    __shared__ float wred[4];

    if (t < OUT_DIM / 4)
        qts4[t] = ((const float4*)(qt + (size_t)b * OUT_DIM))[t];
    __syncthreads();

    // ---- Phase A: scores for CHUNK rows, float4 coalesced k loads ----
    // each 32-lane half-wave handles one row per iteration (8 rows/block/iter)
    const float4* k4 = (const float4*)(k + (size_t)b * SS * OUT_DIM);
    float4 qv = qts4[l32];
    for (int i = wave * 2 + half; i < CHUNK; i += 8) {
        float4 kv = k4[(size_t)(s0 + i) * (OUT_DIM / 4) + l32];
        float p = kv.x * qv.x + kv.y * qv.y + kv.z * qv.z + kv.w * qv.w;
        p += __shfl_xor(p, 1);
        p += __shfl_xor(p, 2);
        p += __shfl_xor(p, 4);
        p += __shfl_xor(p, 8);
        p += __shfl_xor(p, 16);
        if (l32 == 0) sc[i] = p;
    }
    __syncthreads();

    // ---- chunk max ----
    float m = -INFINITY;
    for (int i = t; i < CHUNK; i += 256) m = fmaxf(m, sc[i]);
    for (int d = 1; d < 64; d <<= 1) m = fmaxf(m, __shfl_xor(m, d));
    if (lane == 0) wred[wave] = m;
    __syncthreads();
    m = fmaxf(fmaxf(wred[0], wred[1]), fmaxf(wred[2], wred[3]));
    __syncthreads();  // protect wred reuse

    // ---- exp + chunk sum ----
    float lsum = 0.f;
    for (int i = t; i < CHUNK; i += 256) {
        float e = __expf(sc[i] - m);
        sc[i] = e;
        lsum += e;
    }
    for (int d = 1; d < 64; d <<= 1) lsum += __shfl_xor(lsum, d);
    if (lane == 0) wred[wave] = lsum;
    __syncthreads();  // also makes sc[] (p values) visible to all
    lsum = wred[0] + wred[1] + wred[2] + wred[3];

    // ---- Phase B: partial context, float4 coalesced v loads ----
    int col = t & 31;   // float4 column
    int rg = t >> 5;    // row group 0..7
    const float4* v4 = (const float4*)(v + (size_t)b * SS * DVV);
    float4 acc = make_float4(0.f, 0.f, 0.f, 0.f);
    for (int i = rg; i < CHUNK; i += 8) {
        float p = sc[i];
        float4 vv = v4[(size_t)(s0 + i) * (DVV / 4) + col];
        acc.x = fmaf(p, vv.x, acc.x);
        acc.y = fmaf(p, vv.y, acc.y);
        acc.z = fmaf(p, vv.z, acc.z);
        acc.w = fmaf(p, vv.w, acc.w);
    }
    red[t] = acc;
    __syncthreads();
    for (int off = 128; off >= 32; off >>= 1) {
        if (t < off) {
            float4 o = red[t + off];
            red[t].x += o.x; red[t].y += o.y;
            red[t].z += o.z; red[t].w += o.w;
        }
        __syncthreads();
    }
    if (t < 32)
        ((float4*)(ctx + ((size_t)(b * NCHUNK + c)) * DVV))[t] = red[t];
    if (t == 0) {
        ml[(b * NCHUNK + c) * 2 + 0] = m;
        ml[(b * NCHUNK + c) * 2 + 1] = lsum;
    }
}

// Kernel 3: merge chunk partials with max-rescaling
__global__ void combine_kernel(const float* __restrict__ ml,
                               const float* __restrict__ ctx,
                               float* __restrict__ out) {
    int b = blockIdx.x;
    int t = threadIdx.x;  // 128
    __shared__ float ms, ls;
    float m = -INFINITY;
    if (t < NCHUNK) m = ml[(b * NCHUNK + t) * 2];
    for (int d = 1; d < 32; d <<= 1) m = fmaxf(m, __shfl_xor(m, d));
    if (t == 0) ms = m;
    __syncthreads();
    m = ms;
    float l = 0.f;
    if (t < NCHUNK)
        l = ml[(b * NCHUNK + t) * 2 + 1] * __expf(ml[(b * NCHUNK + t) * 2] - m);
    for (int d = 1; d < 32; d <<= 1) l += __shfl_xor(l, d);
    if (t == 0) ls = l;
    __syncthreads();
    l = ls;
    float acc = 0.f;
    for (int c2 = 0; c2 < NCHUNK; ++c2) {
        float w = __expf(ml[(b * NCHUNK + c2) * 2] - m);
        acc = fmaf(ctx[((size_t)(b * NCHUNK + c2)) * DVV + t], w, acc);
    }
    out[(size_t)b * DVV + t] = acc / l;
}

extern "C" void kernel_launch(void* const* d_in, const int* in_sizes, int n_in,
                              void* d_out, int out_size, void* d_ws, size_t ws_size,
                              hipStream_t stream) {
    const float* k  = (const float*)d_in[0];
    const float* q  = (const float*)d_in[1];
    const float* v  = (const float*)d_in[2];
    const float* Wk = (const float*)d_in[3];
    const float* Wq = (const float*)d_in[4];
    float* out = (float*)d_out;

    float* qt  = (float*)d_ws;                 // B*128 floats
    float* ml  = qt + BB * OUT_DIM;            // B*NCHUNK*2 floats
    float* ctx = ml + BB * NCHUNK * 2;         // B*NCHUNK*128 floats (~1 MB total)

    qt_kernel<<<BB, OUT_DIM, 0, stream>>>(q, Wq, Wk, qt);
    partial_kernel<<<BB * NCHUNK, 256, 0, stream>>>(k, v, qt, ml, ctx);
    combine_kernel<<<BB, DVV, 0, stream>>>(ml, ctx, out);
}